// Round 9
// baseline (177.555 us; speedup 1.0000x reference)
//
#include <hip/hip_runtime.h>
#include <hip/hip_bf16.h>
#include <stdint.h>

#define E_DIM 1024
#define H_NUM 16
#define D_DIM 64
#define B_NUM 4
#define S_LEN 1024

typedef __attribute__((ext_vector_type(8))) short bf16x8;   // 8 bf16, 4 VGPRs
typedef __attribute__((ext_vector_type(4))) short bf16x4;   // 4 bf16, 2 VGPRs
typedef __attribute__((ext_vector_type(4))) float f32x4;

#define SOFTMAX_C2 0.18033688011112042f   // 0.125 * log2(e)

__device__ inline ushort f2b(float x) {
    __hip_bfloat16 h = __float2bfloat16(x);
    return *(ushort*)&h;
}
__device__ inline float b2f(ushort u) {
    __hip_bfloat16 h = *(__hip_bfloat16*)&u;
    return __bfloat162float(h);
}
__device__ inline uint pk2(float a, float b) {
    __hip_bfloat162 h = __float22bfloat162_rn(make_float2(a, b));
    return *(uint*)&h;
}
// raw v_exp_f32 (2^x)
__device__ inline float fexp2(float x) { return __builtin_amdgcn_exp2f(x); }

// async global->LDS, 16 bytes per lane (dest = wave-uniform base + lane*16)
__device__ inline void gld16(const ushort* g, ushort* l) {
    __builtin_amdgcn_global_load_lds((const __attribute__((address_space(1))) void*)g,
                                     (__attribute__((address_space(3))) void*)l, 16, 0, 0);
}

// ---------------------------------------------------------------------------
// One-time fp32 -> bf16 conversion: X (4M), Wq/Wk/Wv -> Wcat (3M), Wo (1M).
// ---------------------------------------------------------------------------
__global__ __launch_bounds__(256)
void convert_all(const float* __restrict__ X,  const float* __restrict__ Wq,
                 const float* __restrict__ Wk, const float* __restrict__ Wv,
                 const float* __restrict__ Wo,
                 ushort* __restrict__ Xb, ushort* __restrict__ Wcat,
                 ushort* __restrict__ Wob)
{
    const int bid = blockIdx.x;
    const float* src; ushort* dst; size_t off;
    if (bid < 4096)      { src = X;  dst = Xb;   off = (size_t)bid * 1024; }
    else if (bid < 5120) { src = Wq; dst = Wcat;              off = (size_t)(bid - 4096) * 1024; }
    else if (bid < 6144) { src = Wk; dst = Wcat + (1u << 20); off = (size_t)(bid - 5120) * 1024; }
    else if (bid < 7168) { src = Wv; dst = Wcat + (2u << 20); off = (size_t)(bid - 6144) * 1024; }
    else                 { src = Wo; dst = Wob;               off = (size_t)(bid - 7168) * 1024; }
    const size_t i = off + (size_t)threadIdx.x * 4;
    float4 v = *(const float4*)&src[i];
    ushort4 o;
    o.x = f2b(v.x); o.y = f2b(v.y); o.z = f2b(v.z); o.w = f2b(v.w);
    *(ushort4*)&dst[i] = o;
}

// ---------------------------------------------------------------------------
// QKV GEMM: 128x128 tile, BK=64, dbuf gld16 with XOR column swizzle.
// XCD-aware 1-D grid (768): xcd = bid&7 owns 4 contiguous m-panels.
// N=3072 fused: Q pre-scaled by 0.125*log2e, K token-major; V transposed
// into Vt_g[bh][d][s] (each block spans 2 heads). Stores 128B-contiguous.
// ---------------------------------------------------------------------------
__global__ __launch_bounds__(256, 2)
void gemm_qkv(const ushort* __restrict__ A, const ushort* __restrict__ Bw,
              const float* __restrict__ b0, const float* __restrict__ b1,
              const float* __restrict__ b2,
              ushort* __restrict__ Qb, ushort* __restrict__ Kb,
              ushort* __restrict__ Vt_g, int K)
{
    __shared__ __align__(16) ushort SM[32768];   // 64 KB
    ushort* As = SM;            // [2][128][64] swizzled
    ushort* Bs = SM + 16384;    // [2][128][64] swizzled

    const int tid  = threadIdx.x;
    const int wave = tid >> 6;
    const int lane = tid & 63;
    const int quad = lane >> 4;
    const int l16  = lane & 15;
    const int wm   = wave & 1;
    const int wn   = wave >> 1;

    // XCD-aware mapping: bid -> (m-panel, n-panel)
    const int bid = blockIdx.x;          // 0..767
    const int xcd = bid & 7;
    const int j   = bid >> 3;            // 0..95
    const int m0  = (xcd * 4 + (j & 3)) * 128;   // 32 m-panels
    const int n0  = (j >> 2) * 128;              // 24 n-panels

    f32x4 acc[4][4] = {};

    auto stageA = [&](int buf, int k0) {
#pragma unroll
        for (int i = 0; i < 4; ++i) {
            const int e   = i * 256 + tid;          // 0..1023
            const int row = e >> 3;
            const int gc8 = ((e & 7) ^ (row & 7)) * 8;
            gld16(&A[(size_t)(m0 + row) * K + k0 + gc8], &As[buf * 8192 + e * 8]);
        }
    };
    auto stageB = [&](int buf, int k0) {
#pragma unroll
        for (int i = 0; i < 4; ++i) {
            const int e   = i * 256 + tid;          // 0..1023
            const int row = e >> 3;
            const int gc8 = ((e & 7) ^ (row & 7)) * 8;
            gld16(&Bw[(size_t)(n0 + row) * K + k0 + gc8], &Bs[buf * 8192 + e * 8]);
        }
    };

    stageA(0, 0); stageB(0, 0);
    __syncthreads();

    const int nk = K >> 6;      // 16
    const int xa = (l16 & 7) * 8;
    for (int ki = 0; ki < nk; ++ki) {
        const int cur = ki & 1;
        if (ki + 1 < nk) { stageA(cur ^ 1, (ki + 1) << 6); stageB(cur ^ 1, (ki + 1) << 6); }

#pragma unroll
        for (int ks = 0; ks < 2; ++ks) {
            const int lc = (ks * 32 + quad * 8) ^ xa;
            bf16x8 af[4], bf[4];
#pragma unroll
            for (int mi = 0; mi < 4; ++mi)
                af[mi] = *(const bf16x8*)&As[cur * 8192 + (wm * 64 + mi * 16 + l16) * 64 + lc];
#pragma unroll
            for (int ni = 0; ni < 4; ++ni)
                bf[ni] = *(const bf16x8*)&Bs[cur * 8192 + (wn * 64 + ni * 16 + l16) * 64 + lc];
#pragma unroll
            for (int mi = 0; mi < 4; ++mi)
#pragma unroll
                for (int ni = 0; ni < 4; ++ni)
                    acc[mi][ni] = __builtin_amdgcn_mfma_f32_16x16x32_bf16(af[mi], bf[ni], acc[mi][ni], 0, 0, 0);
        }
        __syncthreads();
    }

    const int seg   = n0 >> 10;          // 0=Q 1=K 2=V (block-uniform, 8 blocks/seg)
    const int cbase = n0 & 1023;
    const float* bp = (seg == 0) ? b0 : (seg == 1) ? b1 : b2;
    const float scl = (seg == 0) ? SOFTMAX_C2 : 1.0f;

    if (seg < 2) {
        // T[128][136] bf16, then 128B-contiguous row stores
        ushort* T = SM;
#pragma unroll
        for (int ni = 0; ni < 4; ++ni) {
            const int nloc = wn * 64 + ni * 16 + l16;
            const float bv = bp[cbase + nloc];
#pragma unroll
            for (int mi = 0; mi < 4; ++mi)
#pragma unroll
                for (int r = 0; r < 4; ++r)
                    T[(wm * 64 + mi * 16 + quad * 4 + r) * 136 + nloc] =
                        f2b((acc[mi][ni][r] + bv) * scl);
        }
        __syncthreads();
        ushort* dst = (seg == 0) ? Qb : Kb;
        const int row = tid >> 1, half = tid & 1;
        const ushort* s = &T[row * 136 + half * 64];
        ushort* d = &dst[(size_t)(m0 + row) * 1024 + cbase + half * 64];
#pragma unroll
        for (int j2 = 0; j2 < 8; ++j2)
            *(uint4*)(d + j2 * 8) = *(const uint4*)(s + j2 * 8);
    } else {
        // Tt[128][136] bf16 (transposed: d-major), then contiguous stores along s
        ushort* Tt = SM;
        const int b  = m0 >> 10, sbase = m0 & 1023;
#pragma unroll
        for (int ni = 0; ni < 4; ++ni) {
            const int nloc = wn * 64 + ni * 16 + l16;
            const float bv = bp[cbase + nloc];
#pragma unroll
            for (int mi = 0; mi < 4; ++mi) {
                const int mloc = wm * 64 + mi * 16 + quad * 4;
                ushort4 pk;
                pk.x = f2b(acc[mi][ni][0] + bv);
                pk.y = f2b(acc[mi][ni][1] + bv);
                pk.z = f2b(acc[mi][ni][2] + bv);
                pk.w = f2b(acc[mi][ni][3] + bv);
                *(ushort4*)&Tt[nloc * 136 + mloc] = pk;
            }
        }
        __syncthreads();
        const int nrow = tid >> 1, half = tid & 1;      // nrow 0..127 spans 2 heads
        const int hh   = (cbase >> 6) + (nrow >> 6);
        const int drow = nrow & 63;
        const ushort* s = &Tt[nrow * 136 + half * 64];
        ushort* d = &Vt_g[(((size_t)(b * 16 + hh)) * 64 + drow) * 1024 + sbase + half * 64];
#pragma unroll
        for (int j2 = 0; j2 < 8; ++j2)
            *(uint4*)(d + j2 * 8) = *(const uint4*)(s + j2 * 8);
    }
}

// ---------------------------------------------------------------------------
// Flash attention v14 = v11 + counted-vmcnt pipeline (T3/T4-lite).
// __syncthreads drains vmcnt(0) -> every iter paid the K gld16 latency
// serially (the m97 barrier-drain disease). Fix: K = 3-buffer LDS ring
// staged 2 ITERATIONS AHEAD; iteration boundary = s_waitcnt vmcnt(1)
// lgkmcnt(0) + raw s_barrier + sched_barrier(0) -> newest gld16 stays in
// flight across the barrier. Issue order per iter: vpre-load FIRST, then
// gld16, so the compiler's in-order dependence wait for vpre implies the
// older K(kt+1) load completed without draining K(kt+2).
// Last 2 iterations peeled with plain __syncthreads (drain fine at end).
// Grid 1024 = 64 bh x 16 qt, 16q/wave, full t=1024, normalized bf16 out.
// ---------------------------------------------------------------------------
__global__ __launch_bounds__(256, 8)
void attention14(const ushort* __restrict__ Qg, const ushort* __restrict__ Kg,
                 const ushort* __restrict__ Vg, ushort* __restrict__ Anorm)
{
    __shared__ __align__(16) ushort SM[10752];   // 21.5 KB
    // K ring [3][32][64] swizzled @ [0,6144); V dbuf [2][64][36] @ [6144,10752)
    const int VOFF = 6144;

    const int tid  = threadIdx.x;
    const int w    = tid >> 6;
    const int lane = tid & 63;
    const int quad = lane >> 4;
    const int l16  = lane & 15;

    const int gid = blockIdx.x;                      // 0..1023
    const int qt  = (gid >> 3) & 15;
    const int bh  = (gid & 7) | ((gid >> 7) << 3);   // 0..63, constant gid%8
    const int b   = bh >> 4;
    const int h   = bh & 15;
    const size_t tbase = ((size_t)b * S_LEN) * E_DIM + (size_t)h * D_DIM;  // Q/K
    const size_t vbase = (size_t)bh * D_DIM * S_LEN;                       // Vt_g

    const ushort* qrow = Qg + tbase + (size_t)(qt * 64 + w * 16 + l16) * E_DIM + quad * 8;
    bf16x8 qf[2];
    qf[0] = *(const bf16x8*)qrow;
    qf[1] = *(const bf16x8*)(qrow + 32);

    const int krow = tid >> 3, kslot = tid & 7;      // K gld16 mapping
    const int vr   = tid >> 2, vcol = (tid & 3) * 8; // V stage mapping

    const ushort* kptr = Kg + tbase + (size_t)krow * E_DIM + ((kslot ^ (krow & 7)) * 8);
    const ushort* vptr = Vg + vbase + (size_t)vr * S_LEN + vcol;

    // prologue: vpre(0) first, then K(0), K(1) -> dependence wait for vpre
    // leaves K loads in flight; explicit vmcnt(1) ensures K(0) done.
    uint4 vp0 = *(const uint4*)vptr;
    gld16(kptr, &SM[tid * 8]);
    gld16(kptr + 32 * E_DIM, &SM[2048 + tid * 8]);
    kptr += 32 * E_DIM;                              // points at t=32 (= K(1))
    *(uint4*)&SM[VOFF + vr * 36 + vcol] = vp0;
    asm volatile("s_waitcnt vmcnt(1) lgkmcnt(0)" ::: "memory");
    __builtin_amdgcn_s_barrier();
    __builtin_amdgcn_sched_barrier(0);

    float lq = 0.0f;
    f32x4 oacc[4] = {};
    const int xk = (l16 & 7);                        // K read swizzle

    auto compute = [&](int kc, int vb) {
        // ---- S^T[t 32][q 16] = K Q^T (Q pre-scaled) ----
        f32x4 sacc[2] = {};
#pragma unroll
        for (int mt = 0; mt < 2; ++mt)
#pragma unroll
            for (int ks = 0; ks < 2; ++ks) {
                bf16x8 kf = *(const bf16x8*)&SM[kc * 2048 + (mt * 16 + l16) * 64 +
                                                (((ks * 4 + quad) ^ xk) * 8)];
                sacc[mt] = __builtin_amdgcn_mfma_f32_16x16x32_bf16(kf, qf[ks], sacc[mt], 0, 0, 0);
            }

        // ---- p = 2^s; accumulate l; pack A-frags of 16x16x16 ----
        bf16x4 pf[2];
        float rs = 0.0f;
#pragma unroll
        for (int mt = 0; mt < 2; ++mt) {
            float p0 = fexp2(sacc[mt][0]);
            float p1 = fexp2(sacc[mt][1]);
            float p2 = fexp2(sacc[mt][2]);
            float p3 = fexp2(sacc[mt][3]);
            rs += (p0 + p1) + (p2 + p3);
            union { uint uu[2]; bf16x4 v; } pk;
            pk.uu[0] = pk2(p0, p1);
            pk.uu[1] = pk2(p2, p3);
            pf[mt] = pk.v;
        }
        lq += rs;

        // ---- O[q 16][d 64] += P V ----
#pragma unroll
        for (int nb = 0; nb < 4; ++nb)
#pragma unroll
            for (int kb = 0; kb < 2; ++kb) {
                bf16x4 vf = *(const bf16x4*)&SM[VOFF + vb * 2304 +
                                                (nb * 16 + l16) * 36 + kb * 16 + quad * 4];
                oacc[nb] = __builtin_amdgcn_mfma_f32_16x16x16bf16_1k(pf[kb], vf, oacc[nb], 0, 0, 0);
            }
    };

    // main loop: kt = 0..29, K staged 2 ahead, counted-vmcnt barrier
#pragma unroll 6
    for (int kt = 0; kt < 30; ++kt) {
        const int kc = kt % 3;                 // K read buf
        const int kn = (kt + 2) % 3;           // K stage buf
        const int vb = kt & 1;                 // V read buf

        vptr += 32;
        uint4 vpre = *(const uint4*)vptr;      // vpre FIRST (older than gld16)
        kptr += 32 * E_DIM;
        gld16(kptr, &SM[kn * 2048 + tid * 8]); // K(kt+2), stays in flight

        compute(kc, vb);

        *(uint4*)&SM[VOFF + (vb ^ 1) * 2304 + vr * 36 + vcol] = vpre;
        asm volatile("s_waitcnt vmcnt(1) lgkmcnt(0)" ::: "memory");
        __builtin_amdgcn_s_barrier();
        __builtin_amdgcn_sched_barrier(0);
    }

    // kt = 30: no K stage; vpre(31) still needed
    {
        vptr += 32;
        uint4 vpre = *(const uint4*)vptr;
        compute(30 % 3, 0);
        *(uint4*)&SM[VOFF + 2304 + vr * 36 + vcol] = vpre;
        __syncthreads();
    }
    // kt = 31: compute only
    compute(31 % 3, 1);

    // full denominator: butterfly leaves every lane with the total for q=l16
    lq += __shfl_xor(lq, 16);
    lq += __shfl_xor(lq, 32);

    // align l with accumulator rows: oacc row q = quad*4+r, l for q' lives in lane q'
    float linv[4];
#pragma unroll
    for (int r = 0; r < 4; ++r)
        linv[r] = __builtin_amdgcn_rcpf(__shfl(lq, quad * 4 + r));

    __syncthreads();   // waves done reading K/V before T overlays SM

    // normalized O via LDS transpose (T[64][72] overlays SM), coalesced store
    ushort* T = SM;
#pragma unroll
    for (int nb = 0; nb < 4; ++nb)
#pragma unroll
        for (int r = 0; r < 4; ++r)
            T[(w * 16 + quad * 4 + r) * 72 + nb * 16 + l16] = f2b(oacc[nb][r] * linv[r]);
    __syncthreads();
    {
        const int row = tid >> 2, c16 = (tid & 3) * 16;
        const ushort* s = &T[row * 72 + c16];
        ushort* d = &Anorm[(size_t)(b * 1024 + qt * 64 + row) * 1024 + h * 64 + c16];
        *(uint4*)(d)     = *(const uint4*)(s);
        *(uint4*)(d + 8) = *(const uint4*)(s + 8);
    }
}

// ---------------------------------------------------------------------------
// Out-proj: PURE GEMM. C[4096][1024] = Anorm[4096][1024] x Wo^T + bias.
// 128x64 tile, BK=64. XCD-aware 1-D grid (512): each XCD owns 4 m-panels.
// ---------------------------------------------------------------------------
__global__ __launch_bounds__(256, 2)
void gemm_out(const ushort* __restrict__ A, const ushort* __restrict__ Bw,
              const float* __restrict__ bias, float* __restrict__ Cout)
{
    __shared__ __align__(16) ushort SM[24576];   // 48 KB
    ushort* As = SM;            // [2][128][64] swizzled
    ushort* Bs = SM + 16384;    // [2][ 64][64] swizzled

    const int tid  = threadIdx.x;
    const int wave = tid >> 6;
    const int lane = tid & 63;
    const int quad = lane >> 4;
    const int l16  = lane & 15;
    const int wm   = wave & 1;
    const int wn   = wave >> 1;

    // XCD-aware mapping: bid -> (m-panel, n-panel)
    const int bid = blockIdx.x;          // 0..511
    const int xcd = bid & 7;
    const int j   = bid >> 3;            // 0..63
    const int m0  = (xcd * 4 + (j & 3)) * 128;   // 32 m-panels
    const int n0  = (j >> 2) * 64;               // 16 n-panels

    f32x4 acc[4][2] = {};

    auto stageA = [&](int buf, int k0) {
#pragma unroll
        for (int i = 0; i < 4; ++i) {
            const int e   = i * 256 + tid;          // 0..1023
            const int row = e >> 3;
            const int gc8 = ((e & 7) ^ (row & 7)) * 8;
            gld16(&A[(size_t)(m0 + row) * 1024 + k0 + gc8], &As[buf * 8192 + e * 8]);
        }
    };
    auto stageB = [&](int buf, int k0) {
#pragma unroll
        for (int i = 0; i < 2; ++i) {
            const int e   = i * 256 + tid;          // 0..511
            const int row = e >> 3;
            const int gc8 = ((e & 7) ^ (row & 7)) * 8;
            gld16(&Bw[(size_t)(n0 + row) * 1024 + k0 + gc8], &Bs[buf * 4096 + e * 8]);
        }
    };

    stageA(0, 0); stageB(0, 0);
    __syncthreads();

    const int xa = (l16 & 7) * 8;
    for (int ki = 0; ki < 16; ++ki) {
        const int cur = ki & 1;
        if (ki + 1 < 16) { stageA(cur ^ 1, (ki + 1) << 6); stageB(cur ^ 1, (ki + 1) << 6); }

#pragma unroll
        for (int ks = 0; ks < 2; ++ks) {
            const int lc = (ks * 32 + quad * 8) ^ xa;
            bf16x8 af[4], bf[2];
#pragma unroll
            for (int mi = 0; mi < 4; ++mi)
                af[mi] = *(const bf16x8*)&As[cur * 8192 + (wm * 64 + mi * 16 + l16) * 64 + lc];
#pragma unroll
            for (int ni = 0; ni < 2; ++ni)
                bf[ni] = *(const bf16x8*)&Bs[cur * 4096 + (wn * 32 + ni * 16 + l16) * 64 + lc];
#pragma unroll
            for (int mi = 0; mi < 4; ++mi)
#pragma unroll
                for (int ni = 0; ni < 2; ++ni)
                    acc[mi][ni] = __builtin_amdgcn_mfma_f32_16x16x32_bf16(af[mi], bf[ni], acc[mi][ni], 0, 0, 0);
        }
        __syncthreads();
    }

    // fp32 LDS-transpose epilogue (Tf[128][68] = 34.8 KB overlays SM)
    float* Tf = (float*)SM;
#pragma unroll
    for (int ni = 0; ni < 2; ++ni) {
        const int nloc = wn * 32 + ni * 16 + l16;
        const float bv = bias[n0 + nloc];
#pragma unroll
        for (int mi = 0; mi < 4; ++mi)
#pragma unroll
            for (int r = 0; r < 4; ++r)
                Tf[(wm * 64 + mi * 16 + quad * 4 + r) * 68 + nloc] = acc[mi][ni][r] + bv;
    }
    __syncthreads();
    {
        const int row = tid >> 1, half = tid & 1;   // rows 0..127
        const float* s = &Tf[row * 68 + half * 32];
        float* d = &Cout[(size_t)(m0 + row) * 1024 + n0 + half * 32];
#pragma unroll
        for (int j2 = 0; j2 < 8; ++j2)
            *(float4*)(d + j2 * 4) = *(const float4*)(s + j2 * 4);
    }
}

// ---------------------------------------------------------------------------
extern "C" void kernel_launch(void* const* d_in, const int* in_sizes, int n_in,
                              void* d_out, int out_size, void* d_ws, size_t ws_size,
                              hipStream_t stream)
{
    (void)in_sizes; (void)n_in; (void)out_size; (void)ws_size;

    const float* X  = (const float*)d_in[0];
    const float* Wq = (const float*)d_in[1];
    const float* bq = (const float*)d_in[2];
    const float* Wk = (const float*)d_in[3];
    const float* bk = (const float*)d_in[4];
    const float* Wv = (const float*)d_in[5];
    const float* bv = (const float*)d_in[6];
    const float* Wo = (const float*)d_in[7];
    const float* bo = (const float*)d_in[8];

    const size_t MEG = 1u << 20;
    ushort* ws    = (ushort*)d_ws;
    ushort* Xb    = ws;               // 4M
    ushort* Wcat  = ws + 4 * MEG;     // 3M  (Wq;Wk;Wv)
    ushort* Wob   = ws + 7 * MEG;     // 1M
    ushort* Qb    = ws + 8 * MEG;     // 4M  (pre-scaled by 0.125*log2e)
    ushort* Kb    = ws + 12 * MEG;    // 4M
    ushort* Vtg   = ws + 16 * MEG;    // 4M  [bh][d][s]
    ushort* Anorm = ws + 20 * MEG;    // 4M ushorts = [4096 tok][1024] bf16

    dim3 blk(256);

    convert_all<<<8192, blk, 0, stream>>>(X, Wq, Wk, Wv, Wo, Xb, Wcat, Wob);

    gemm_qkv<<<768, blk, 0, stream>>>(Xb, Wcat, bq, bk, bv,
                                      Qb, Kb, Vtg, E_DIM);

    attention14<<<1024, blk, 0, stream>>>(Qb, Kb, Vtg, Anorm);

    gemm_out<<<512, blk, 0, stream>>>(Anorm, Wob, bo, (float*)d_out);
}

// Round 10
// 172.772 us; speedup vs baseline: 1.0277x; 1.0277x over previous
//
#include <hip/hip_runtime.h>
#include <hip/hip_bf16.h>
#include <stdint.h>

#define E_DIM 1024
#define H_NUM 16
#define D_DIM 64
#define B_NUM 4
#define S_LEN 1024

typedef __attribute__((ext_vector_type(8))) short bf16x8;   // 8 bf16, 4 VGPRs
typedef __attribute__((ext_vector_type(4))) short bf16x4;   // 4 bf16, 2 VGPRs
typedef __attribute__((ext_vector_type(4))) float f32x4;

#define SOFTMAX_C2 0.18033688011112042f   // 0.125 * log2(e)

__device__ inline ushort f2b(float x) {
    __hip_bfloat16 h = __float2bfloat16(x);
    return *(ushort*)&h;
}
__device__ inline float b2f(ushort u) {
    __hip_bfloat16 h = *(__hip_bfloat16*)&u;
    return __bfloat162float(h);
}
__device__ inline uint pk2(float a, float b) {
    __hip_bfloat162 h = __float22bfloat162_rn(make_float2(a, b));
    return *(uint*)&h;
}
// raw v_exp_f32 (2^x)
__device__ inline float fexp2(float x) { return __builtin_amdgcn_exp2f(x); }

// cheap packed f32->2xbf16, round-half-up: u+=0x8000 then v_perm splices the
// two hi16 halves. 3 VALU vs ~10 for the header's software-RNE pk2. Differs
// from RNE only on exact 0x8000 ties (measure-zero for exp2 outputs).
__device__ inline uint pk2h(float a, float b) {
    uint ua = __builtin_bit_cast(uint, a) + 0x8000u;
    uint ub = __builtin_bit_cast(uint, b) + 0x8000u;
    return __builtin_amdgcn_perm(ub, ua, 0x07060302u);  // {ub.hi16, ua.hi16}
}

// async global->LDS, 16 bytes per lane (dest = wave-uniform base + lane*16)
__device__ inline void gld16(const ushort* g, ushort* l) {
    __builtin_amdgcn_global_load_lds((const __attribute__((address_space(1))) void*)g,
                                     (__attribute__((address_space(3))) void*)l, 16, 0, 0);
}

// ---------------------------------------------------------------------------
// One-time fp32 -> bf16 conversion: X (4M), Wq/Wk/Wv -> Wcat (3M), Wo (1M).
// ---------------------------------------------------------------------------
__global__ __launch_bounds__(256)
void convert_all(const float* __restrict__ X,  const float* __restrict__ Wq,
                 const float* __restrict__ Wk, const float* __restrict__ Wv,
                 const float* __restrict__ Wo,
                 ushort* __restrict__ Xb, ushort* __restrict__ Wcat,
                 ushort* __restrict__ Wob)
{
    const int bid = blockIdx.x;
    const float* src; ushort* dst; size_t off;
    if (bid < 4096)      { src = X;  dst = Xb;   off = (size_t)bid * 1024; }
    else if (bid < 5120) { src = Wq; dst = Wcat;              off = (size_t)(bid - 4096) * 1024; }
    else if (bid < 6144) { src = Wk; dst = Wcat + (1u << 20); off = (size_t)(bid - 5120) * 1024; }
    else if (bid < 7168) { src = Wv; dst = Wcat + (2u << 20); off = (size_t)(bid - 6144) * 1024; }
    else                 { src = Wo; dst = Wob;               off = (size_t)(bid - 7168) * 1024; }
    const size_t i = off + (size_t)threadIdx.x * 4;
    float4 v = *(const float4*)&src[i];
    ushort4 o;
    o.x = f2b(v.x); o.y = f2b(v.y); o.z = f2b(v.z); o.w = f2b(v.w);
    *(ushort4*)&dst[i] = o;
}

// ---------------------------------------------------------------------------
// QKV GEMM: 128x128 tile, BK=64, dbuf gld16 with XOR column swizzle.
// XCD-aware 1-D grid (768): xcd = bid&7 owns 4 contiguous m-panels.
// N=3072 fused: Q pre-scaled by 0.125*log2e, K token-major; V transposed
// into Vt_g[bh][d][s] (each block spans 2 heads). Stores 128B-contiguous.
// ---------------------------------------------------------------------------
__global__ __launch_bounds__(256, 2)
void gemm_qkv(const ushort* __restrict__ A, const ushort* __restrict__ Bw,
              const float* __restrict__ b0, const float* __restrict__ b1,
              const float* __restrict__ b2,
              ushort* __restrict__ Qb, ushort* __restrict__ Kb,
              ushort* __restrict__ Vt_g, int K)
{
    __shared__ __align__(16) ushort SM[32768];   // 64 KB
    ushort* As = SM;            // [2][128][64] swizzled
    ushort* Bs = SM + 16384;    // [2][128][64] swizzled

    const int tid  = threadIdx.x;
    const int wave = tid >> 6;
    const int lane = tid & 63;
    const int quad = lane >> 4;
    const int l16  = lane & 15;
    const int wm   = wave & 1;
    const int wn   = wave >> 1;

    // XCD-aware mapping: bid -> (m-panel, n-panel)
    const int bid = blockIdx.x;          // 0..767
    const int xcd = bid & 7;
    const int j   = bid >> 3;            // 0..95
    const int m0  = (xcd * 4 + (j & 3)) * 128;   // 32 m-panels
    const int n0  = (j >> 2) * 128;              // 24 n-panels

    f32x4 acc[4][4] = {};

    auto stageA = [&](int buf, int k0) {
#pragma unroll
        for (int i = 0; i < 4; ++i) {
            const int e   = i * 256 + tid;          // 0..1023
            const int row = e >> 3;
            const int gc8 = ((e & 7) ^ (row & 7)) * 8;
            gld16(&A[(size_t)(m0 + row) * K + k0 + gc8], &As[buf * 8192 + e * 8]);
        }
    };
    auto stageB = [&](int buf, int k0) {
#pragma unroll
        for (int i = 0; i < 4; ++i) {
            const int e   = i * 256 + tid;          // 0..1023
            const int row = e >> 3;
            const int gc8 = ((e & 7) ^ (row & 7)) * 8;
            gld16(&Bw[(size_t)(n0 + row) * K + k0 + gc8], &Bs[buf * 8192 + e * 8]);
        }
    };

    stageA(0, 0); stageB(0, 0);
    __syncthreads();

    const int nk = K >> 6;      // 16
    const int xa = (l16 & 7) * 8;
    for (int ki = 0; ki < nk; ++ki) {
        const int cur = ki & 1;
        if (ki + 1 < nk) { stageA(cur ^ 1, (ki + 1) << 6); stageB(cur ^ 1, (ki + 1) << 6); }

#pragma unroll
        for (int ks = 0; ks < 2; ++ks) {
            const int lc = (ks * 32 + quad * 8) ^ xa;
            bf16x8 af[4], bf[4];
#pragma unroll
            for (int mi = 0; mi < 4; ++mi)
                af[mi] = *(const bf16x8*)&As[cur * 8192 + (wm * 64 + mi * 16 + l16) * 64 + lc];
#pragma unroll
            for (int ni = 0; ni < 4; ++ni)
                bf[ni] = *(const bf16x8*)&Bs[cur * 8192 + (wn * 64 + ni * 16 + l16) * 64 + lc];
#pragma unroll
            for (int mi = 0; mi < 4; ++mi)
#pragma unroll
                for (int ni = 0; ni < 4; ++ni)
                    acc[mi][ni] = __builtin_amdgcn_mfma_f32_16x16x32_bf16(af[mi], bf[ni], acc[mi][ni], 0, 0, 0);
        }
        __syncthreads();
    }

    const int seg   = n0 >> 10;          // 0=Q 1=K 2=V (block-uniform, 8 blocks/seg)
    const int cbase = n0 & 1023;
    const float* bp = (seg == 0) ? b0 : (seg == 1) ? b1 : b2;
    const float scl = (seg == 0) ? SOFTMAX_C2 : 1.0f;

    if (seg < 2) {
        // T[128][136] bf16, then 128B-contiguous row stores
        ushort* T = SM;
#pragma unroll
        for (int ni = 0; ni < 4; ++ni) {
            const int nloc = wn * 64 + ni * 16 + l16;
            const float bv = bp[cbase + nloc];
#pragma unroll
            for (int mi = 0; mi < 4; ++mi)
#pragma unroll
                for (int r = 0; r < 4; ++r)
                    T[(wm * 64 + mi * 16 + quad * 4 + r) * 136 + nloc] =
                        f2b((acc[mi][ni][r] + bv) * scl);
        }
        __syncthreads();
        ushort* dst = (seg == 0) ? Qb : Kb;
        const int row = tid >> 1, half = tid & 1;
        const ushort* s = &T[row * 136 + half * 64];
        ushort* d = &dst[(size_t)(m0 + row) * 1024 + cbase + half * 64];
#pragma unroll
        for (int j2 = 0; j2 < 8; ++j2)
            *(uint4*)(d + j2 * 8) = *(const uint4*)(s + j2 * 8);
    } else {
        // Tt[128][136] bf16 (transposed: d-major), then contiguous stores along s
        ushort* Tt = SM;
        const int b  = m0 >> 10, sbase = m0 & 1023;
#pragma unroll
        for (int ni = 0; ni < 4; ++ni) {
            const int nloc = wn * 64 + ni * 16 + l16;
            const float bv = bp[cbase + nloc];
#pragma unroll
            for (int mi = 0; mi < 4; ++mi) {
                const int mloc = wm * 64 + mi * 16 + quad * 4;
                ushort4 pk;
                pk.x = f2b(acc[mi][ni][0] + bv);
                pk.y = f2b(acc[mi][ni][1] + bv);
                pk.z = f2b(acc[mi][ni][2] + bv);
                pk.w = f2b(acc[mi][ni][3] + bv);
                *(ushort4*)&Tt[nloc * 136 + mloc] = pk;
            }
        }
        __syncthreads();
        const int nrow = tid >> 1, half = tid & 1;      // nrow 0..127 spans 2 heads
        const int hh   = (cbase >> 6) + (nrow >> 6);
        const int drow = nrow & 63;
        const ushort* s = &Tt[nrow * 136 + half * 64];
        ushort* d = &Vt_g[(((size_t)(b * 16 + hh)) * 64 + drow) * 1024 + sbase + half * 64];
#pragma unroll
        for (int j2 = 0; j2 < 8; ++j2)
            *(uint4*)(d + j2 * 8) = *(const uint4*)(s + j2 * 8);
    }
}

// ---------------------------------------------------------------------------
// Flash attention v15 = v11 (R8-best structure) with the P-pack VALU diet:
// pk2 (software-RNE, ~10 VALU/pair) -> pk2h (add+add+v_perm, 3 VALU/pair).
// LDS-staged, no t-split, 16q/wave, grid 1024 = 64 bh x 16 qt, 4 blocks/CU.
// Full t=1024 per block (32 K-tiles); normalized O stored token-major.
// XCD swizzle: all 16 qt of one bh share gid%8 -> same XCD -> K/V L2 reuse.
// ---------------------------------------------------------------------------
__global__ __launch_bounds__(256, 8)
void attention15(const ushort* __restrict__ Qg, const ushort* __restrict__ Kg,
                 const ushort* __restrict__ Vg, ushort* __restrict__ Anorm)
{
    __shared__ __align__(16) ushort SM[9216];   // 18.4 KB
    // K dbuf [2][32][64] swizzled @ [0,4096); V dbuf [2][64][36] @ [4096,8704)

    const int tid  = threadIdx.x;
    const int w    = tid >> 6;
    const int lane = tid & 63;
    const int quad = lane >> 4;
    const int l16  = lane & 15;

    const int gid = blockIdx.x;                      // 0..1023
    const int qt  = (gid >> 3) & 15;
    const int bh  = (gid & 7) | ((gid >> 7) << 3);   // 0..63, constant gid%8
    const int b   = bh >> 4;
    const int h   = bh & 15;
    const size_t tbase = ((size_t)b * S_LEN) * E_DIM + (size_t)h * D_DIM;  // Q/K
    const size_t vbase = (size_t)bh * D_DIM * S_LEN;                       // Vt_g

    const ushort* qrow = Qg + tbase + (size_t)(qt * 64 + w * 16 + l16) * E_DIM + quad * 8;
    bf16x8 qf[2];
    qf[0] = *(const bf16x8*)qrow;
    qf[1] = *(const bf16x8*)(qrow + 32);

    const int krow = tid >> 3, kslot = tid & 7;      // K gld16 mapping
    const int vr   = tid >> 2, vc = (tid & 3) * 8;   // V stage mapping

    // hand-bumped staging pointers
    const ushort* kptr = Kg + tbase + (size_t)krow * E_DIM + ((kslot ^ (krow & 7)) * 8);
    const ushort* vptr = Vg + vbase + (size_t)vr * S_LEN + vc;

    gld16(kptr, &SM[tid * 8]);
    {
        uint4 v0 = *(const uint4*)vptr;
        *(uint4*)&SM[4096 + vr * 36 + vc] = v0;
    }
    __syncthreads();

    float lq = 0.0f;
    f32x4 oacc[4] = {};
    const int xk = (l16 & 7);                        // K read swizzle

    for (int kt = 0; kt < 32; ++kt) {
        const int cur = kt & 1;

        uint4 vpre;
        if (kt < 31) {
            kptr += 32 * E_DIM;
            gld16(kptr, &SM[(cur ^ 1) * 2048 + tid * 8]);
            vptr += 32;
            vpre = *(const uint4*)vptr;
        }

        // ---- S^T[t 32][q 16] = K Q^T (Q pre-scaled) ----
        f32x4 sacc[2] = {};
#pragma unroll
        for (int mt = 0; mt < 2; ++mt)
#pragma unroll
            for (int ks = 0; ks < 2; ++ks) {
                bf16x8 kf = *(const bf16x8*)&SM[cur * 2048 + (mt * 16 + l16) * 64 +
                                                (((ks * 4 + quad) ^ xk) * 8)];
                sacc[mt] = __builtin_amdgcn_mfma_f32_16x16x32_bf16(kf, qf[ks], sacc[mt], 0, 0, 0);
            }

        // ---- p = 2^s; accumulate l; pack A-frags of 16x16x16 (pk2h) ----
        bf16x4 pf[2];
        float rs = 0.0f;
#pragma unroll
        for (int mt = 0; mt < 2; ++mt) {
            float p0 = fexp2(sacc[mt][0]);
            float p1 = fexp2(sacc[mt][1]);
            float p2 = fexp2(sacc[mt][2]);
            float p3 = fexp2(sacc[mt][3]);
            rs += (p0 + p1) + (p2 + p3);
            union { uint uu[2]; bf16x4 v; } pk;
            pk.uu[0] = pk2h(p0, p1);
            pk.uu[1] = pk2h(p2, p3);
            pf[mt] = pk.v;
        }
        lq += rs;

        // ---- O[q 16][d 64] += P V ----
#pragma unroll
        for (int nb = 0; nb < 4; ++nb)
#pragma unroll
            for (int kb = 0; kb < 2; ++kb) {
                bf16x4 vf = *(const bf16x4*)&SM[4096 + cur * 2304 +
                                                (nb * 16 + l16) * 36 + kb * 16 + quad * 4];
                oacc[nb] = __builtin_amdgcn_mfma_f32_16x16x16bf16_1k(pf[kb], vf, oacc[nb], 0, 0, 0);
            }

        if (kt < 31)
            *(uint4*)&SM[4096 + (cur ^ 1) * 2304 + vr * 36 + vc] = vpre;
        __syncthreads();
    }

    // full denominator: butterfly leaves every lane with the total for q=l16
    lq += __shfl_xor(lq, 16);
    lq += __shfl_xor(lq, 32);

    // align l with accumulator rows: oacc row q = quad*4+r, l for q' lives in lane q'
    float linv[4];
#pragma unroll
    for (int r = 0; r < 4; ++r)
        linv[r] = __builtin_amdgcn_rcpf(__shfl(lq, quad * 4 + r));

    // normalized O via LDS transpose (T[64][72] overlays SM), coalesced store
    ushort* T = SM;
#pragma unroll
    for (int nb = 0; nb < 4; ++nb)
#pragma unroll
        for (int r = 0; r < 4; ++r)
            T[(w * 16 + quad * 4 + r) * 72 + nb * 16 + l16] = f2b(oacc[nb][r] * linv[r]);
    __syncthreads();
    {
        const int row = tid >> 2, c16 = (tid & 3) * 16;
        const ushort* s = &T[row * 72 + c16];
        ushort* d = &Anorm[(size_t)(b * 1024 + qt * 64 + row) * 1024 + h * 64 + c16];
        *(uint4*)(d)     = *(const uint4*)(s);
        *(uint4*)(d + 8) = *(const uint4*)(s + 8);
    }
}

// ---------------------------------------------------------------------------
// Out-proj: PURE GEMM. C[4096][1024] = Anorm[4096][1024] x Wo^T + bias.
// 128x64 tile, BK=64. XCD-aware 1-D grid (512): each XCD owns 4 m-panels.
// ---------------------------------------------------------------------------
__global__ __launch_bounds__(256, 2)
void gemm_out(const ushort* __restrict__ A, const ushort* __restrict__ Bw,
              const float* __restrict__ bias, float* __restrict__ Cout)
{
    __shared__ __align__(16) ushort SM[24576];   // 48 KB
    ushort* As = SM;            // [2][128][64] swizzled
    ushort* Bs = SM + 16384;    // [2][ 64][64] swizzled

    const int tid  = threadIdx.x;
    const int wave = tid >> 6;
    const int lane = tid & 63;
    const int quad = lane >> 4;
    const int l16  = lane & 15;
    const int wm   = wave & 1;
    const int wn   = wave >> 1;

    // XCD-aware mapping: bid -> (m-panel, n-panel)
    const int bid = blockIdx.x;          // 0..511
    const int xcd = bid & 7;
    const int j   = bid >> 3;            // 0..63
    const int m0  = (xcd * 4 + (j & 3)) * 128;   // 32 m-panels
    const int n0  = (j >> 2) * 64;               // 16 n-panels

    f32x4 acc[4][2] = {};

    auto stageA = [&](int buf, int k0) {
#pragma unroll
        for (int i = 0; i < 4; ++i) {
            const int e   = i * 256 + tid;          // 0..1023
            const int row = e >> 3;
            const int gc8 = ((e & 7) ^ (row & 7)) * 8;
            gld16(&A[(size_t)(m0 + row) * 1024 + k0 + gc8], &As[buf * 8192 + e * 8]);
        }
    };
    auto stageB = [&](int buf, int k0) {
#pragma unroll
        for (int i = 0; i < 2; ++i) {
            const int e   = i * 256 + tid;          // 0..511
            const int row = e >> 3;
            const int gc8 = ((e & 7) ^ (row & 7)) * 8;
            gld16(&Bw[(size_t)(n0 + row) * 1024 + k0 + gc8], &Bs[buf * 4096 + e * 8]);
        }
    };

    stageA(0, 0); stageB(0, 0);
    __syncthreads();

    const int xa = (l16 & 7) * 8;
    for (int ki = 0; ki < 16; ++ki) {
        const int cur = ki & 1;
        if (ki + 1 < 16) { stageA(cur ^ 1, (ki + 1) << 6); stageB(cur ^ 1, (ki + 1) << 6); }

#pragma unroll
        for (int ks = 0; ks < 2; ++ks) {
            const int lc = (ks * 32 + quad * 8) ^ xa;
            bf16x8 af[4], bf[2];
#pragma unroll
            for (int mi = 0; mi < 4; ++mi)
                af[mi] = *(const bf16x8*)&As[cur * 8192 + (wm * 64 + mi * 16 + l16) * 64 + lc];
#pragma unroll
            for (int ni = 0; ni < 2; ++ni)
                bf[ni] = *(const bf16x8*)&Bs[cur * 4096 + (wn * 32 + ni * 16 + l16) * 64 + lc];
#pragma unroll
            for (int mi = 0; mi < 4; ++mi)
#pragma unroll
                for (int ni = 0; ni < 2; ++ni)
                    acc[mi][ni] = __builtin_amdgcn_mfma_f32_16x16x32_bf16(af[mi], bf[ni], acc[mi][ni], 0, 0, 0);
        }
        __syncthreads();
    }

    // fp32 LDS-transpose epilogue (Tf[128][68] = 34.8 KB overlays SM)
    float* Tf = (float*)SM;
#pragma unroll
    for (int ni = 0; ni < 2; ++ni) {
        const int nloc = wn * 32 + ni * 16 + l16;
        const float bv = bias[n0 + nloc];
#pragma unroll
        for (int mi = 0; mi < 4; ++mi)
#pragma unroll
            for (int r = 0; r < 4; ++r)
                Tf[(wm * 64 + mi * 16 + quad * 4 + r) * 68 + nloc] = acc[mi][ni][r] + bv;
    }
    __syncthreads();
    {
        const int row = tid >> 1, half = tid & 1;   // rows 0..127
        const float* s = &Tf[row * 68 + half * 32];
        float* d = &Cout[(size_t)(m0 + row) * 1024 + n0 + half * 32];
#pragma unroll
        for (int j2 = 0; j2 < 8; ++j2)
            *(float4*)(d + j2 * 4) = *(const float4*)(s + j2 * 4);
    }
}

// ---------------------------------------------------------------------------
extern "C" void kernel_launch(void* const* d_in, const int* in_sizes, int n_in,
                              void* d_out, int out_size, void* d_ws, size_t ws_size,
                              hipStream_t stream)
{
    (void)in_sizes; (void)n_in; (void)out_size; (void)ws_size;

    const float* X  = (const float*)d_in[0];
    const float* Wq = (const float*)d_in[1];
    const float* bq = (const float*)d_in[2];
    const float* Wk = (const float*)d_in[3];
    const float* bk = (const float*)d_in[4];
    const float* Wv = (const float*)d_in[5];
    const float* bv = (const float*)d_in[6];
    const float* Wo = (const float*)d_in[7];
    const float* bo = (const float*)d_in[8];

    const size_t MEG = 1u << 20;
    ushort* ws    = (ushort*)d_ws;
    ushort* Xb    = ws;               // 4M
    ushort* Wcat  = ws + 4 * MEG;     // 3M  (Wq;Wk;Wv)
    ushort* Wob   = ws + 7 * MEG;     // 1M
    ushort* Qb    = ws + 8 * MEG;     // 4M  (pre-scaled by 0.125*log2e)
    ushort* Kb    = ws + 12 * MEG;    // 4M
    ushort* Vtg   = ws + 16 * MEG;    // 4M  [bh][d][s]
    ushort* Anorm = ws + 20 * MEG;    // 4M ushorts = [4096 tok][1024] bf16

    dim3 blk(256);

    convert_all<<<8192, blk, 0, stream>>>(X, Wq, Wk, Wv, Wo, Xb, Wcat, Wob);

    gemm_qkv<<<768, blk, 0, stream>>>(Xb, Wcat, bq, bk, bv,
                                      Qb, Kb, Vtg, E_DIM);

    attention15<<<1024, blk, 0, stream>>>(Qb, Kb, Vtg, Anorm);

    gemm_out<<<512, blk, 0, stream>>>(Anorm, Wob, bo, (float*)d_out);
}

// Round 11
// 171.390 us; speedup vs baseline: 1.0360x; 1.0081x over previous
//
#include <hip/hip_runtime.h>
#include <hip/hip_bf16.h>
#include <stdint.h>

#define E_DIM 1024
#define H_NUM 16
#define D_DIM 64
#define B_NUM 4
#define S_LEN 1024

typedef __attribute__((ext_vector_type(8))) short bf16x8;   // 8 bf16, 4 VGPRs
typedef __attribute__((ext_vector_type(4))) short bf16x4;   // 4 bf16, 2 VGPRs
typedef __attribute__((ext_vector_type(4))) float f32x4;

#define SOFTMAX_C2 0.18033688011112042f   // 0.125 * log2(e)

__device__ inline ushort f2b(float x) {
    __hip_bfloat16 h = __float2bfloat16(x);
    return *(ushort*)&h;
}
__device__ inline float b2f(ushort u) {
    __hip_bfloat16 h = *(__hip_bfloat16*)&u;
    return __bfloat162float(h);
}
__device__ inline uint pk2(float a, float b) {
    __hip_bfloat162 h = __float22bfloat162_rn(make_float2(a, b));
    return *(uint*)&h;
}
// raw v_exp_f32 (2^x)
__device__ inline float fexp2(float x) { return __builtin_amdgcn_exp2f(x); }

// cheap packed f32->2xbf16, round-half-up: u+=0x8000 then v_perm splices the
// two hi16 halves. 3 VALU vs ~10 for the header's software-RNE pk2.
__device__ inline uint pk2h(float a, float b) {
    uint ua = __builtin_bit_cast(uint, a) + 0x8000u;
    uint ub = __builtin_bit_cast(uint, b) + 0x8000u;
    return __builtin_amdgcn_perm(ub, ua, 0x07060302u);  // {ub.hi16, ua.hi16}
}

// async global->LDS, 16 bytes per lane (dest = wave-uniform base + lane*16)
__device__ inline void gld16(const ushort* g, ushort* l) {
    __builtin_amdgcn_global_load_lds((const __attribute__((address_space(1))) void*)g,
                                     (__attribute__((address_space(3))) void*)l, 16, 0, 0);
}

// ---------------------------------------------------------------------------
// One-time fp32 -> bf16 conversion: X (4M), Wq/Wk/Wv -> Wcat (3M), Wo (1M).
// ---------------------------------------------------------------------------
__global__ __launch_bounds__(256)
void convert_all(const float* __restrict__ X,  const float* __restrict__ Wq,
                 const float* __restrict__ Wk, const float* __restrict__ Wv,
                 const float* __restrict__ Wo,
                 ushort* __restrict__ Xb, ushort* __restrict__ Wcat,
                 ushort* __restrict__ Wob)
{
    const int bid = blockIdx.x;
    const float* src; ushort* dst; size_t off;
    if (bid < 4096)      { src = X;  dst = Xb;   off = (size_t)bid * 1024; }
    else if (bid < 5120) { src = Wq; dst = Wcat;              off = (size_t)(bid - 4096) * 1024; }
    else if (bid < 6144) { src = Wk; dst = Wcat + (1u << 20); off = (size_t)(bid - 5120) * 1024; }
    else if (bid < 7168) { src = Wv; dst = Wcat + (2u << 20); off = (size_t)(bid - 6144) * 1024; }
    else                 { src = Wo; dst = Wob;               off = (size_t)(bid - 7168) * 1024; }
    const size_t i = off + (size_t)threadIdx.x * 4;
    float4 v = *(const float4*)&src[i];
    ushort4 o;
    o.x = f2b(v.x); o.y = f2b(v.y); o.z = f2b(v.z); o.w = f2b(v.w);
    *(ushort4*)&dst[i] = o;
}

// ---------------------------------------------------------------------------
// QKV GEMM: 128x128 tile, BK=64, dbuf gld16 with XOR column swizzle.
// XCD-aware 1-D grid (768): xcd = bid&7 owns 4 contiguous m-panels.
// N=3072 fused: Q pre-scaled by 0.125*log2e, K token-major; V transposed
// into Vt_g[bh][d][s] (each block spans 2 heads). Stores 128B-contiguous.
// ---------------------------------------------------------------------------
__global__ __launch_bounds__(256, 2)
void gemm_qkv(const ushort* __restrict__ A, const ushort* __restrict__ Bw,
              const float* __restrict__ b0, const float* __restrict__ b1,
              const float* __restrict__ b2,
              ushort* __restrict__ Qb, ushort* __restrict__ Kb,
              ushort* __restrict__ Vt_g, int K)
{
    __shared__ __align__(16) ushort SM[32768];   // 64 KB
    ushort* As = SM;            // [2][128][64] swizzled
    ushort* Bs = SM + 16384;    // [2][128][64] swizzled

    const int tid  = threadIdx.x;
    const int wave = tid >> 6;
    const int lane = tid & 63;
    const int quad = lane >> 4;
    const int l16  = lane & 15;
    const int wm   = wave & 1;
    const int wn   = wave >> 1;

    // XCD-aware mapping: bid -> (m-panel, n-panel)
    const int bid = blockIdx.x;          // 0..767
    const int xcd = bid & 7;
    const int j   = bid >> 3;            // 0..95
    const int m0  = (xcd * 4 + (j & 3)) * 128;   // 32 m-panels
    const int n0  = (j >> 2) * 128;              // 24 n-panels

    f32x4 acc[4][4] = {};

    auto stageA = [&](int buf, int k0) {
#pragma unroll
        for (int i = 0; i < 4; ++i) {
            const int e   = i * 256 + tid;          // 0..1023
            const int row = e >> 3;
            const int gc8 = ((e & 7) ^ (row & 7)) * 8;
            gld16(&A[(size_t)(m0 + row) * K + k0 + gc8], &As[buf * 8192 + e * 8]);
        }
    };
    auto stageB = [&](int buf, int k0) {
#pragma unroll
        for (int i = 0; i < 4; ++i) {
            const int e   = i * 256 + tid;          // 0..1023
            const int row = e >> 3;
            const int gc8 = ((e & 7) ^ (row & 7)) * 8;
            gld16(&Bw[(size_t)(n0 + row) * K + k0 + gc8], &Bs[buf * 8192 + e * 8]);
        }
    };

    stageA(0, 0); stageB(0, 0);
    __syncthreads();

    const int nk = K >> 6;      // 16
    const int xa = (l16 & 7) * 8;
    for (int ki = 0; ki < nk; ++ki) {
        const int cur = ki & 1;
        if (ki + 1 < nk) { stageA(cur ^ 1, (ki + 1) << 6); stageB(cur ^ 1, (ki + 1) << 6); }

#pragma unroll
        for (int ks = 0; ks < 2; ++ks) {
            const int lc = (ks * 32 + quad * 8) ^ xa;
            bf16x8 af[4], bf[4];
#pragma unroll
            for (int mi = 0; mi < 4; ++mi)
                af[mi] = *(const bf16x8*)&As[cur * 8192 + (wm * 64 + mi * 16 + l16) * 64 + lc];
#pragma unroll
            for (int ni = 0; ni < 4; ++ni)
                bf[ni] = *(const bf16x8*)&Bs[cur * 8192 + (wn * 64 + ni * 16 + l16) * 64 + lc];
#pragma unroll
            for (int mi = 0; mi < 4; ++mi)
#pragma unroll
                for (int ni = 0; ni < 4; ++ni)
                    acc[mi][ni] = __builtin_amdgcn_mfma_f32_16x16x32_bf16(af[mi], bf[ni], acc[mi][ni], 0, 0, 0);
        }
        __syncthreads();
    }

    const int seg   = n0 >> 10;          // 0=Q 1=K 2=V (block-uniform, 8 blocks/seg)
    const int cbase = n0 & 1023;
    const float* bp = (seg == 0) ? b0 : (seg == 1) ? b1 : b2;
    const float scl = (seg == 0) ? SOFTMAX_C2 : 1.0f;

    if (seg < 2) {
        // T[128][136] bf16, then 128B-contiguous row stores
        ushort* T = SM;
#pragma unroll
        for (int ni = 0; ni < 4; ++ni) {
            const int nloc = wn * 64 + ni * 16 + l16;
            const float bv = bp[cbase + nloc];
#pragma unroll
            for (int mi = 0; mi < 4; ++mi)
#pragma unroll
                for (int r = 0; r < 4; ++r)
                    T[(wm * 64 + mi * 16 + quad * 4 + r) * 136 + nloc] =
                        f2b((acc[mi][ni][r] + bv) * scl);
        }
        __syncthreads();
        ushort* dst = (seg == 0) ? Qb : Kb;
        const int row = tid >> 1, half = tid & 1;
        const ushort* s = &T[row * 136 + half * 64];
        ushort* d = &dst[(size_t)(m0 + row) * 1024 + cbase + half * 64];
#pragma unroll
        for (int j2 = 0; j2 < 8; ++j2)
            *(uint4*)(d + j2 * 8) = *(const uint4*)(s + j2 * 8);
    } else {
        // Tt[128][136] bf16 (transposed: d-major), then contiguous stores along s
        ushort* Tt = SM;
        const int b  = m0 >> 10, sbase = m0 & 1023;
#pragma unroll
        for (int ni = 0; ni < 4; ++ni) {
            const int nloc = wn * 64 + ni * 16 + l16;
            const float bv = bp[cbase + nloc];
#pragma unroll
            for (int mi = 0; mi < 4; ++mi) {
                const int mloc = wm * 64 + mi * 16 + quad * 4;
                ushort4 pk;
                pk.x = f2b(acc[mi][ni][0] + bv);
                pk.y = f2b(acc[mi][ni][1] + bv);
                pk.z = f2b(acc[mi][ni][2] + bv);
                pk.w = f2b(acc[mi][ni][3] + bv);
                *(ushort4*)&Tt[nloc * 136 + mloc] = pk;
            }
        }
        __syncthreads();
        const int nrow = tid >> 1, half = tid & 1;      // nrow 0..127 spans 2 heads
        const int hh   = (cbase >> 6) + (nrow >> 6);
        const int drow = nrow & 63;
        const ushort* s = &Tt[nrow * 136 + half * 64];
        ushort* d = &Vt_g[(((size_t)(b * 16 + hh)) * 64 + drow) * 1024 + sbase + half * 64];
#pragma unroll
        for (int j2 = 0; j2 < 8; ++j2)
            *(uint4*)(d + j2 * 8) = *(const uint4*)(s + j2 * 8);
    }
}

// ---------------------------------------------------------------------------
// Flash attention v16 = v15 with KVBLK 32 -> 64 (m214 ladder: +27% there).
// Halves barrier-separated iterations (32 -> 16): per-iteration sync/loop
// overhead paid half as often, prefetch issued a 2x-longer compute ahead.
// K dbuf [2][64][64] swizzled (2 gld16/thread/iter); V dbuf [2][64][68]
// (2 uint4/thread/iter; 68-pad: dword-bank = 2*row mod 32, conflict-free).
// LDS 33.8 KB -> 4 blocks/CU at grid 1024. pk2h P-pack kept.
// 16q/wave, full t=1024, normalized bf16 O stored token-major.
// XCD swizzle: all 16 qt of one bh share gid%8 -> same XCD -> K/V L2 reuse.
// ---------------------------------------------------------------------------
__global__ __launch_bounds__(256, 4)
void attention16(const ushort* __restrict__ Qg, const ushort* __restrict__ Kg,
                 const ushort* __restrict__ Vg, ushort* __restrict__ Anorm)
{
    __shared__ __align__(16) ushort SM[16896];   // 33.8 KB
    // K dbuf [2][64][64] swizzled @ [0,8192); V dbuf [2][64][68] @ [8192,16896)
    const int VOFF = 8192;

    const int tid  = threadIdx.x;
    const int w    = tid >> 6;
    const int lane = tid & 63;
    const int quad = lane >> 4;
    const int l16  = lane & 15;

    const int gid = blockIdx.x;                      // 0..1023
    const int qt  = (gid >> 3) & 15;
    const int bh  = (gid & 7) | ((gid >> 7) << 3);   // 0..63, constant gid%8
    const int b   = bh >> 4;
    const int h   = bh & 15;
    const size_t tbase = ((size_t)b * S_LEN) * E_DIM + (size_t)h * D_DIM;  // Q/K
    const size_t vbase = (size_t)bh * D_DIM * S_LEN;                       // Vt_g

    const ushort* qrow = Qg + tbase + (size_t)(qt * 64 + w * 16 + l16) * E_DIM + quad * 8;
    bf16x8 qf[2];
    qf[0] = *(const bf16x8*)qrow;
    qf[1] = *(const bf16x8*)(qrow + 32);

    const int krow = tid >> 3, kslot = tid & 7;      // K gld16 mapping (rows 0..31, +32)
    const int vr   = tid >> 2, vc = (tid & 3) * 8;   // V stage mapping (64 rows, 2x32 cols)

    // hand-bumped staging pointers
    const ushort* kptr = Kg + tbase + (size_t)krow * E_DIM + ((kslot ^ (krow & 7)) * 8);
    const ushort* vptr = Vg + vbase + (size_t)vr * S_LEN + vc;

    // prologue: stage tile 0
    gld16(kptr,              &SM[tid * 8]);
    gld16(kptr + 32 * E_DIM, &SM[(256 + tid) * 8]);
    {
        uint4 v0 = *(const uint4*)vptr;
        uint4 v1 = *(const uint4*)(vptr + 32);
        *(uint4*)&SM[VOFF + vr * 68 + vc]      = v0;
        *(uint4*)&SM[VOFF + vr * 68 + vc + 32] = v1;
    }
    __syncthreads();

    float lq = 0.0f;
    f32x4 oacc[4] = {};
    const int xk = (l16 & 7);                        // K read swizzle

    for (int kt = 0; kt < 16; ++kt) {
        const int cur = kt & 1;

        uint4 vpre0, vpre1;
        if (kt < 15) {
            kptr += 64 * E_DIM;
            gld16(kptr,              &SM[(cur ^ 1) * 4096 + tid * 8]);
            gld16(kptr + 32 * E_DIM, &SM[(cur ^ 1) * 4096 + (256 + tid) * 8]);
            vptr += 64;
            vpre0 = *(const uint4*)vptr;
            vpre1 = *(const uint4*)(vptr + 32);
        }

        // ---- S^T[t 64][q 16] = K Q^T (Q pre-scaled) ----
        f32x4 sacc[4] = {};
#pragma unroll
        for (int mt = 0; mt < 4; ++mt)
#pragma unroll
            for (int ks = 0; ks < 2; ++ks) {
                bf16x8 kf = *(const bf16x8*)&SM[cur * 4096 + (mt * 16 + l16) * 64 +
                                                (((ks * 4 + quad) ^ xk) * 8)];
                sacc[mt] = __builtin_amdgcn_mfma_f32_16x16x32_bf16(kf, qf[ks], sacc[mt], 0, 0, 0);
            }

        // ---- p = 2^s; accumulate l; pack A-frags of 16x16x16 (pk2h) ----
        bf16x4 pf[4];
        float rs = 0.0f;
#pragma unroll
        for (int mt = 0; mt < 4; ++mt) {
            float p0 = fexp2(sacc[mt][0]);
            float p1 = fexp2(sacc[mt][1]);
            float p2 = fexp2(sacc[mt][2]);
            float p3 = fexp2(sacc[mt][3]);
            rs += (p0 + p1) + (p2 + p3);
            union { uint uu[2]; bf16x4 v; } pk;
            pk.uu[0] = pk2h(p0, p1);
            pk.uu[1] = pk2h(p2, p3);
            pf[mt] = pk.v;
        }
        lq += rs;

        // ---- O[q 16][d 64] += P V (K=64 split into 4 k-groups) ----
#pragma unroll
        for (int nb = 0; nb < 4; ++nb)
#pragma unroll
            for (int kb = 0; kb < 4; ++kb) {
                bf16x4 vf = *(const bf16x4*)&SM[VOFF + cur * 4352 +
                                                (nb * 16 + l16) * 68 + kb * 16 + quad * 4];
                oacc[nb] = __builtin_amdgcn_mfma_f32_16x16x16bf16_1k(pf[kb], vf, oacc[nb], 0, 0, 0);
            }

        if (kt < 15) {
            *(uint4*)&SM[VOFF + (cur ^ 1) * 4352 + vr * 68 + vc]      = vpre0;
            *(uint4*)&SM[VOFF + (cur ^ 1) * 4352 + vr * 68 + vc + 32] = vpre1;
        }
        __syncthreads();
    }

    // full denominator: butterfly leaves every lane with the total for q=l16
    lq += __shfl_xor(lq, 16);
    lq += __shfl_xor(lq, 32);

    // align l with accumulator rows: oacc row q = quad*4+r, l for q' lives in lane q'
    float linv[4];
#pragma unroll
    for (int r = 0; r < 4; ++r)
        linv[r] = __builtin_amdgcn_rcpf(__shfl(lq, quad * 4 + r));

    // normalized O via LDS transpose (T[64][72] overlays SM), coalesced store
    ushort* T = SM;
#pragma unroll
    for (int nb = 0; nb < 4; ++nb)
#pragma unroll
        for (int r = 0; r < 4; ++r)
            T[(w * 16 + quad * 4 + r) * 72 + nb * 16 + l16] = f2b(oacc[nb][r] * linv[r]);
    __syncthreads();
    {
        const int row = tid >> 2, c16 = (tid & 3) * 16;
        const ushort* s = &T[row * 72 + c16];
        ushort* d = &Anorm[(size_t)(b * 1024 + qt * 64 + row) * 1024 + h * 64 + c16];
        *(uint4*)(d)     = *(const uint4*)(s);
        *(uint4*)(d + 8) = *(const uint4*)(s + 8);
    }
}

// ---------------------------------------------------------------------------
// Out-proj: PURE GEMM. C[4096][1024] = Anorm[4096][1024] x Wo^T + bias.
// 128x64 tile, BK=64. XCD-aware 1-D grid (512): each XCD owns 4 m-panels.
// ---------------------------------------------------------------------------
__global__ __launch_bounds__(256, 2)
void gemm_out(const ushort* __restrict__ A, const ushort* __restrict__ Bw,
              const float* __restrict__ bias, float* __restrict__ Cout)
{
    __shared__ __align__(16) ushort SM[24576];   // 48 KB
    ushort* As = SM;            // [2][128][64] swizzled
    ushort* Bs = SM + 16384;    // [2][ 64][64] swizzled

    const int tid  = threadIdx.x;
    const int wave = tid >> 6;
    const int lane = tid & 63;
    const int quad = lane >> 4;
    const int l16  = lane & 15;
    const int wm   = wave & 1;
    const int wn   = wave >> 1;

    // XCD-aware mapping: bid -> (m-panel, n-panel)
    const int bid = blockIdx.x;          // 0..511
    const int xcd = bid & 7;
    const int j   = bid >> 3;            // 0..63
    const int m0  = (xcd * 4 + (j & 3)) * 128;   // 32 m-panels
    const int n0  = (j >> 2) * 64;               // 16 n-panels

    f32x4 acc[4][2] = {};

    auto stageA = [&](int buf, int k0) {
#pragma unroll
        for (int i = 0; i < 4; ++i) {
            const int e   = i * 256 + tid;          // 0..1023
            const int row = e >> 3;
            const int gc8 = ((e & 7) ^ (row & 7)) * 8;
            gld16(&A[(size_t)(m0 + row) * 1024 + k0 + gc8], &As[buf * 8192 + e * 8]);
        }
    };
    auto stageB = [&](int buf, int k0) {
#pragma unroll
        for (int i = 0; i < 2; ++i) {
            const int e   = i * 256 + tid;          // 0..511
            const int row = e >> 3;
            const int gc8 = ((e & 7) ^ (row & 7)) * 8;
            gld16(&Bw[(size_t)(n0 + row) * 1024 + k0 + gc8], &Bs[buf * 4096 + e * 8]);
        }
    };

    stageA(0, 0); stageB(0, 0);
    __syncthreads();

    const int xa = (l16 & 7) * 8;
    for (int ki = 0; ki < 16; ++ki) {
        const int cur = ki & 1;
        if (ki + 1 < 16) { stageA(cur ^ 1, (ki + 1) << 6); stageB(cur ^ 1, (ki + 1) << 6); }

#pragma unroll
        for (int ks = 0; ks < 2; ++ks) {
            const int lc = (ks * 32 + quad * 8) ^ xa;
            bf16x8 af[4], bf[2];
#pragma unroll
            for (int mi = 0; mi < 4; ++mi)
                af[mi] = *(const bf16x8*)&As[cur * 8192 + (wm * 64 + mi * 16 + l16) * 64 + lc];
#pragma unroll
            for (int ni = 0; ni < 2; ++ni)
                bf[ni] = *(const bf16x8*)&Bs[cur * 4096 + (wn * 32 + ni * 16 + l16) * 64 + lc];
#pragma unroll
            for (int mi = 0; mi < 4; ++mi)
#pragma unroll
                for (int ni = 0; ni < 2; ++ni)
                    acc[mi][ni] = __builtin_amdgcn_mfma_f32_16x16x32_bf16(af[mi], bf[ni], acc[mi][ni], 0, 0, 0);
        }
        __syncthreads();
    }

    // fp32 LDS-transpose epilogue (Tf[128][68] = 34.8 KB overlays SM)
    float* Tf = (float*)SM;
#pragma unroll
    for (int ni = 0; ni < 2; ++ni) {
        const int nloc = wn * 32 + ni * 16 + l16;
        const float bv = bias[n0 + nloc];
#pragma unroll
        for (int mi = 0; mi < 4; ++mi)
#pragma unroll
            for (int r = 0; r < 4; ++r)
                Tf[(wm * 64 + mi * 16 + quad * 4 + r) * 68 + nloc] = acc[mi][ni][r] + bv;
    }
    __syncthreads();
    {
        const int row = tid >> 1, half = tid & 1;   // rows 0..127
        const float* s = &Tf[row * 68 + half * 32];
        float* d = &Cout[(size_t)(m0 + row) * 1024 + n0 + half * 32];
#pragma unroll
        for (int j2 = 0; j2 < 8; ++j2)
            *(float4*)(d + j2 * 4) = *(const float4*)(s + j2 * 4);
    }
}

// ---------------------------------------------------------------------------
extern "C" void kernel_launch(void* const* d_in, const int* in_sizes, int n_in,
                              void* d_out, int out_size, void* d_ws, size_t ws_size,
                              hipStream_t stream)
{
    (void)in_sizes; (void)n_in; (void)out_size; (void)ws_size;

    const float* X  = (const float*)d_in[0];
    const float* Wq = (const float*)d_in[1];
    const float* bq = (const float*)d_in[2];
    const float* Wk = (const float*)d_in[3];
    const float* bk = (const float*)d_in[4];
    const float* Wv = (const float*)d_in[5];
    const float* bv = (const float*)d_in[6];
    const float* Wo = (const float*)d_in[7];
    const float* bo = (const float*)d_in[8];

    const size_t MEG = 1u << 20;
    ushort* ws    = (ushort*)d_ws;
    ushort* Xb    = ws;               // 4M
    ushort* Wcat  = ws + 4 * MEG;     // 3M  (Wq;Wk;Wv)
    ushort* Wob   = ws + 7 * MEG;     // 1M
    ushort* Qb    = ws + 8 * MEG;     // 4M  (pre-scaled by 0.125*log2e)
    ushort* Kb    = ws + 12 * MEG;    // 4M
    ushort* Vtg   = ws + 16 * MEG;    // 4M  [bh][d][s]
    ushort* Anorm = ws + 20 * MEG;    // 4M ushorts = [4096 tok][1024] bf16

    dim3 blk(256);

    convert_all<<<8192, blk, 0, stream>>>(X, Wq, Wk, Wv, Wo, Xb, Wcat, Wob);

    gemm_qkv<<<768, blk, 0, stream>>>(Xb, Wcat, bq, bk, bv,
                                      Qb, Kb, Vtg, E_DIM);

    attention16<<<1024, blk, 0, stream>>>(Qb, Kb, Vtg, Anorm);

    gemm_out<<<512, blk, 0, stream>>>(Anorm, Wob, bo, (float*)d_out);
}

// Round 12
// 169.037 us; speedup vs baseline: 1.0504x; 1.0139x over previous
//
#include <hip/hip_runtime.h>
#include <hip/hip_bf16.h>
#include <stdint.h>

#define E_DIM 1024
#define H_NUM 16
#define D_DIM 64
#define B_NUM 4
#define S_LEN 1024

typedef __attribute__((ext_vector_type(8))) short bf16x8;   // 8 bf16, 4 VGPRs
typedef __attribute__((ext_vector_type(4))) short bf16x4;   // 4 bf16, 2 VGPRs
typedef __attribute__((ext_vector_type(4))) float f32x4;

#define SOFTMAX_C2 0.18033688011112042f   // 0.125 * log2(e)

__device__ inline ushort f2b(float x) {
    __hip_bfloat16 h = __float2bfloat16(x);
    return *(ushort*)&h;
}
__device__ inline float b2f(ushort u) {
    __hip_bfloat16 h = *(__hip_bfloat16*)&u;
    return __bfloat162float(h);
}
__device__ inline uint pk2(float a, float b) {
    __hip_bfloat162 h = __float22bfloat162_rn(make_float2(a, b));
    return *(uint*)&h;
}
// raw v_exp_f32 (2^x)
__device__ inline float fexp2(float x) { return __builtin_amdgcn_exp2f(x); }

// cheap packed f32->2xbf16, round-half-up: u+=0x8000 then v_perm splices the
// two hi16 halves. 3 VALU vs ~10 for the header's software-RNE pk2.
__device__ inline uint pk2h(float a, float b) {
    uint ua = __builtin_bit_cast(uint, a) + 0x8000u;
    uint ub = __builtin_bit_cast(uint, b) + 0x8000u;
    return __builtin_amdgcn_perm(ub, ua, 0x07060302u);  // {ub.hi16, ua.hi16}
}

// async global->LDS, 16 bytes per lane (dest = wave-uniform base + lane*16)
__device__ inline void gld16(const ushort* g, ushort* l) {
    __builtin_amdgcn_global_load_lds((const __attribute__((address_space(1))) void*)g,
                                     (__attribute__((address_space(3))) void*)l, 16, 0, 0);
}

// ---------------------------------------------------------------------------
// One-time fp32 -> bf16 conversion: X (4M), Wq/Wk/Wv -> Wcat (3M), Wo (1M).
// ---------------------------------------------------------------------------
__global__ __launch_bounds__(256)
void convert_all(const float* __restrict__ X,  const float* __restrict__ Wq,
                 const float* __restrict__ Wk, const float* __restrict__ Wv,
                 const float* __restrict__ Wo,
                 ushort* __restrict__ Xb, ushort* __restrict__ Wcat,
                 ushort* __restrict__ Wob)
{
    const int bid = blockIdx.x;
    const float* src; ushort* dst; size_t off;
    if (bid < 4096)      { src = X;  dst = Xb;   off = (size_t)bid * 1024; }
    else if (bid < 5120) { src = Wq; dst = Wcat;              off = (size_t)(bid - 4096) * 1024; }
    else if (bid < 6144) { src = Wk; dst = Wcat + (1u << 20); off = (size_t)(bid - 5120) * 1024; }
    else if (bid < 7168) { src = Wv; dst = Wcat + (2u << 20); off = (size_t)(bid - 6144) * 1024; }
    else                 { src = Wo; dst = Wob;               off = (size_t)(bid - 7168) * 1024; }
    const size_t i = off + (size_t)threadIdx.x * 4;
    float4 v = *(const float4*)&src[i];
    ushort4 o;
    o.x = f2b(v.x); o.y = f2b(v.y); o.z = f2b(v.z); o.w = f2b(v.w);
    *(ushort4*)&dst[i] = o;
}

// ---------------------------------------------------------------------------
// QKV GEMM v3 = m97 structure: 128x128 tile, BK=64, SINGLE-buffered 32 KB
// stage (two barriers/K-step). R11 counters showed the dbuf 64 KB version
// was latency-bound at 2 blocks/CU (MfmaUtil 19%, fetch BW 0.68 TB/s,
// occupancy 14%): not enough resident waves to hide the vmcnt(0) drain.
// Single-buffer -> 34.8 KB LDS (epilogue overlay is the max) -> 4 blocks/CU;
// implicit wave-level overlap across blocks hides staging latency [m114].
// XCD-aware 1-D grid (768), n-INNER within XCD: the 1 MB A panel stays hot
// in the XCD's L2 across consecutive blocks while B streams.
// N=3072 fused: Q pre-scaled by 0.125*log2e, K token-major; V transposed
// into Vt_g[bh][d][s] (each block spans 2 heads). Stores 128B-contiguous.
// ---------------------------------------------------------------------------
__global__ __launch_bounds__(256, 4)
void gemm_qkv(const ushort* __restrict__ A, const ushort* __restrict__ Bw,
              const float* __restrict__ b0, const float* __restrict__ b1,
              const float* __restrict__ b2,
              ushort* __restrict__ Qb, ushort* __restrict__ Kb,
              ushort* __restrict__ Vt_g, int K)
{
    __shared__ __align__(16) ushort SM[17408];   // 34.8 KB (epilogue needs it)
    ushort* As = SM;            // [128][64] swizzled (16 KB)
    ushort* Bs = SM + 8192;     // [128][64] swizzled (16 KB)

    const int tid  = threadIdx.x;
    const int wave = tid >> 6;
    const int lane = tid & 63;
    const int quad = lane >> 4;
    const int l16  = lane & 15;
    const int wm   = wave & 1;
    const int wn   = wave >> 1;

    // XCD-aware mapping, n-inner: xcd owns 4 m-panels; consecutive j share m
    const int bid = blockIdx.x;          // 0..767
    const int xcd = bid & 7;
    const int j   = bid >> 3;            // 0..95
    const int jm  = j / 24;              // 0..3
    const int jn  = j - jm * 24;         // 0..23
    const int m0  = (xcd * 4 + jm) * 128;
    const int n0  = jn * 128;

    f32x4 acc[4][4] = {};

    auto stageA = [&](int k0) {
#pragma unroll
        for (int i = 0; i < 4; ++i) {
            const int e   = i * 256 + tid;          // 0..1023
            const int row = e >> 3;
            const int gc8 = ((e & 7) ^ (row & 7)) * 8;
            gld16(&A[(size_t)(m0 + row) * K + k0 + gc8], &As[e * 8]);
        }
    };
    auto stageB = [&](int k0) {
#pragma unroll
        for (int i = 0; i < 4; ++i) {
            const int e   = i * 256 + tid;          // 0..1023
            const int row = e >> 3;
            const int gc8 = ((e & 7) ^ (row & 7)) * 8;
            gld16(&Bw[(size_t)(n0 + row) * K + k0 + gc8], &Bs[e * 8]);
        }
    };

    const int nk = K >> 6;      // 16
    const int xa = (l16 & 7) * 8;
    for (int ki = 0; ki < nk; ++ki) {
        stageA(ki << 6); stageB(ki << 6);
        __syncthreads();

#pragma unroll
        for (int ks = 0; ks < 2; ++ks) {
            const int lc = (ks * 32 + quad * 8) ^ xa;
            bf16x8 af[4], bf[4];
#pragma unroll
            for (int mi = 0; mi < 4; ++mi)
                af[mi] = *(const bf16x8*)&As[(wm * 64 + mi * 16 + l16) * 64 + lc];
#pragma unroll
            for (int ni = 0; ni < 4; ++ni)
                bf[ni] = *(const bf16x8*)&Bs[(wn * 64 + ni * 16 + l16) * 64 + lc];
#pragma unroll
            for (int mi = 0; mi < 4; ++mi)
#pragma unroll
                for (int ni = 0; ni < 4; ++ni)
                    acc[mi][ni] = __builtin_amdgcn_mfma_f32_16x16x32_bf16(af[mi], bf[ni], acc[mi][ni], 0, 0, 0);
        }
        __syncthreads();
    }

    const int seg   = n0 >> 10;          // 0=Q 1=K 2=V (block-uniform, 8 blocks/seg)
    const int cbase = n0 & 1023;
    const float* bp = (seg == 0) ? b0 : (seg == 1) ? b1 : b2;
    const float scl = (seg == 0) ? SOFTMAX_C2 : 1.0f;

    if (seg < 2) {
        // T[128][136] bf16, then 128B-contiguous row stores
        ushort* T = SM;
#pragma unroll
        for (int ni = 0; ni < 4; ++ni) {
            const int nloc = wn * 64 + ni * 16 + l16;
            const float bv = bp[cbase + nloc];
#pragma unroll
            for (int mi = 0; mi < 4; ++mi)
#pragma unroll
                for (int r = 0; r < 4; ++r)
                    T[(wm * 64 + mi * 16 + quad * 4 + r) * 136 + nloc] =
                        f2b((acc[mi][ni][r] + bv) * scl);
        }
        __syncthreads();
        ushort* dst = (seg == 0) ? Qb : Kb;
        const int row = tid >> 1, half = tid & 1;
        const ushort* s = &T[row * 136 + half * 64];
        ushort* d = &dst[(size_t)(m0 + row) * 1024 + cbase + half * 64];
#pragma unroll
        for (int j2 = 0; j2 < 8; ++j2)
            *(uint4*)(d + j2 * 8) = *(const uint4*)(s + j2 * 8);
    } else {
        // Tt[128][136] bf16 (transposed: d-major), then contiguous stores along s
        ushort* Tt = SM;
        const int b  = m0 >> 10, sbase = m0 & 1023;
#pragma unroll
        for (int ni = 0; ni < 4; ++ni) {
            const int nloc = wn * 64 + ni * 16 + l16;
            const float bv = bp[cbase + nloc];
#pragma unroll
            for (int mi = 0; mi < 4; ++mi) {
                const int mloc = wm * 64 + mi * 16 + quad * 4;
                ushort4 pk;
                pk.x = f2b(acc[mi][ni][0] + bv);
                pk.y = f2b(acc[mi][ni][1] + bv);
                pk.z = f2b(acc[mi][ni][2] + bv);
                pk.w = f2b(acc[mi][ni][3] + bv);
                *(ushort4*)&Tt[nloc * 136 + mloc] = pk;
            }
        }
        __syncthreads();
        const int nrow = tid >> 1, half = tid & 1;      // nrow 0..127 spans 2 heads
        const int hh   = (cbase >> 6) + (nrow >> 6);
        const int drow = nrow & 63;
        const ushort* s = &Tt[nrow * 136 + half * 64];
        ushort* d = &Vt_g[(((size_t)(b * 16 + hh)) * 64 + drow) * 1024 + sbase + half * 64];
#pragma unroll
        for (int j2 = 0; j2 < 8; ++j2)
            *(uint4*)(d + j2 * 8) = *(const uint4*)(s + j2 * 8);
    }
}

// ---------------------------------------------------------------------------
// Flash attention v16: KVBLK=64, 16 barrier iterations. K dbuf [2][64][64]
// swizzled; V dbuf [2][64][68]. LDS 33.8 KB -> 4 blocks/CU at grid 1024.
// pk2h P-pack. 16q/wave, full t=1024, normalized bf16 O token-major.
// XCD swizzle: all 16 qt of one bh share gid%8 -> same XCD -> K/V L2 reuse.
// ---------------------------------------------------------------------------
__global__ __launch_bounds__(256, 4)
void attention16(const ushort* __restrict__ Qg, const ushort* __restrict__ Kg,
                 const ushort* __restrict__ Vg, ushort* __restrict__ Anorm)
{
    __shared__ __align__(16) ushort SM[16896];   // 33.8 KB
    // K dbuf [2][64][64] swizzled @ [0,8192); V dbuf [2][64][68] @ [8192,16896)
    const int VOFF = 8192;

    const int tid  = threadIdx.x;
    const int w    = tid >> 6;
    const int lane = tid & 63;
    const int quad = lane >> 4;
    const int l16  = lane & 15;

    const int gid = blockIdx.x;                      // 0..1023
    const int qt  = (gid >> 3) & 15;
    const int bh  = (gid & 7) | ((gid >> 7) << 3);   // 0..63, constant gid%8
    const int b   = bh >> 4;
    const int h   = bh & 15;
    const size_t tbase = ((size_t)b * S_LEN) * E_DIM + (size_t)h * D_DIM;  // Q/K
    const size_t vbase = (size_t)bh * D_DIM * S_LEN;                       // Vt_g

    const ushort* qrow = Qg + tbase + (size_t)(qt * 64 + w * 16 + l16) * E_DIM + quad * 8;
    bf16x8 qf[2];
    qf[0] = *(const bf16x8*)qrow;
    qf[1] = *(const bf16x8*)(qrow + 32);

    const int krow = tid >> 3, kslot = tid & 7;      // K gld16 mapping (rows 0..31, +32)
    const int vr   = tid >> 2, vc = (tid & 3) * 8;   // V stage mapping (64 rows, 2x32 cols)

    // hand-bumped staging pointers
    const ushort* kptr = Kg + tbase + (size_t)krow * E_DIM + ((kslot ^ (krow & 7)) * 8);
    const ushort* vptr = Vg + vbase + (size_t)vr * S_LEN + vc;

    // prologue: stage tile 0
    gld16(kptr,              &SM[tid * 8]);
    gld16(kptr + 32 * E_DIM, &SM[(256 + tid) * 8]);
    {
        uint4 v0 = *(const uint4*)vptr;
        uint4 v1 = *(const uint4*)(vptr + 32);
        *(uint4*)&SM[VOFF + vr * 68 + vc]      = v0;
        *(uint4*)&SM[VOFF + vr * 68 + vc + 32] = v1;
    }
    __syncthreads();

    float lq = 0.0f;
    f32x4 oacc[4] = {};
    const int xk = (l16 & 7);                        // K read swizzle

    for (int kt = 0; kt < 16; ++kt) {
        const int cur = kt & 1;

        uint4 vpre0, vpre1;
        if (kt < 15) {
            kptr += 64 * E_DIM;
            gld16(kptr,              &SM[(cur ^ 1) * 4096 + tid * 8]);
            gld16(kptr + 32 * E_DIM, &SM[(cur ^ 1) * 4096 + (256 + tid) * 8]);
            vptr += 64;
            vpre0 = *(const uint4*)vptr;
            vpre1 = *(const uint4*)(vptr + 32);
        }

        // ---- S^T[t 64][q 16] = K Q^T (Q pre-scaled) ----
        f32x4 sacc[4] = {};
#pragma unroll
        for (int mt = 0; mt < 4; ++mt)
#pragma unroll
            for (int ks = 0; ks < 2; ++ks) {
                bf16x8 kf = *(const bf16x8*)&SM[cur * 4096 + (mt * 16 + l16) * 64 +
                                                (((ks * 4 + quad) ^ xk) * 8)];
                sacc[mt] = __builtin_amdgcn_mfma_f32_16x16x32_bf16(kf, qf[ks], sacc[mt], 0, 0, 0);
            }

        // ---- p = 2^s; accumulate l; pack A-frags of 16x16x16 (pk2h) ----
        bf16x4 pf[4];
        float rs = 0.0f;
#pragma unroll
        for (int mt = 0; mt < 4; ++mt) {
            float p0 = fexp2(sacc[mt][0]);
            float p1 = fexp2(sacc[mt][1]);
            float p2 = fexp2(sacc[mt][2]);
            float p3 = fexp2(sacc[mt][3]);
            rs += (p0 + p1) + (p2 + p3);
            union { uint uu[2]; bf16x4 v; } pk;
            pk.uu[0] = pk2h(p0, p1);
            pk.uu[1] = pk2h(p2, p3);
            pf[mt] = pk.v;
        }
        lq += rs;

        // ---- O[q 16][d 64] += P V (K=64 split into 4 k-groups) ----
#pragma unroll
        for (int nb = 0; nb < 4; ++nb)
#pragma unroll
            for (int kb = 0; kb < 4; ++kb) {
                bf16x4 vf = *(const bf16x4*)&SM[VOFF + cur * 4352 +
                                                (nb * 16 + l16) * 68 + kb * 16 + quad * 4];
                oacc[nb] = __builtin_amdgcn_mfma_f32_16x16x16bf16_1k(pf[kb], vf, oacc[nb], 0, 0, 0);
            }

        if (kt < 15) {
            *(uint4*)&SM[VOFF + (cur ^ 1) * 4352 + vr * 68 + vc]      = vpre0;
            *(uint4*)&SM[VOFF + (cur ^ 1) * 4352 + vr * 68 + vc + 32] = vpre1;
        }
        __syncthreads();
    }

    // full denominator: butterfly leaves every lane with the total for q=l16
    lq += __shfl_xor(lq, 16);
    lq += __shfl_xor(lq, 32);

    // align l with accumulator rows: oacc row q = quad*4+r, l for q' lives in lane q'
    float linv[4];
#pragma unroll
    for (int r = 0; r < 4; ++r)
        linv[r] = __builtin_amdgcn_rcpf(__shfl(lq, quad * 4 + r));

    // normalized O via LDS transpose (T[64][72] overlays SM), coalesced store
    ushort* T = SM;
#pragma unroll
    for (int nb = 0; nb < 4; ++nb)
#pragma unroll
        for (int r = 0; r < 4; ++r)
            T[(w * 16 + quad * 4 + r) * 72 + nb * 16 + l16] = f2b(oacc[nb][r] * linv[r]);
    __syncthreads();
    {
        const int row = tid >> 2, c16 = (tid & 3) * 16;
        const ushort* s = &T[row * 72 + c16];
        ushort* d = &Anorm[(size_t)(b * 1024 + qt * 64 + row) * 1024 + h * 64 + c16];
        *(uint4*)(d)     = *(const uint4*)(s);
        *(uint4*)(d + 8) = *(const uint4*)(s + 8);
    }
}

// ---------------------------------------------------------------------------
// Out-proj: PURE GEMM. C[4096][1024] = Anorm[4096][1024] x Wo^T + bias.
// 128x64 tile, BK=64. XCD-aware 1-D grid (512): each XCD owns 4 m-panels.
// ---------------------------------------------------------------------------
__global__ __launch_bounds__(256, 2)
void gemm_out(const ushort* __restrict__ A, const ushort* __restrict__ Bw,
              const float* __restrict__ bias, float* __restrict__ Cout)
{
    __shared__ __align__(16) ushort SM[24576];   // 48 KB
    ushort* As = SM;            // [2][128][64] swizzled
    ushort* Bs = SM + 16384;    // [2][ 64][64] swizzled

    const int tid  = threadIdx.x;
    const int wave = tid >> 6;
    const int lane = tid & 63;
    const int quad = lane >> 4;
    const int l16  = lane & 15;
    const int wm   = wave & 1;
    const int wn   = wave >> 1;

    // XCD-aware mapping: bid -> (m-panel, n-panel)
    const int bid = blockIdx.x;          // 0..511
    const int xcd = bid & 7;
    const int j   = bid >> 3;            // 0..63
    const int m0  = (xcd * 4 + (j & 3)) * 128;   // 32 m-panels
    const int n0  = (j >> 2) * 64;               // 16 n-panels

    f32x4 acc[4][2] = {};

    auto stageA = [&](int buf, int k0) {
#pragma unroll
        for (int i = 0; i < 4; ++i) {
            const int e   = i * 256 + tid;          // 0..1023
            const int row = e >> 3;
            const int gc8 = ((e & 7) ^ (row & 7)) * 8;
            gld16(&A[(size_t)(m0 + row) * 1024 + k0 + gc8], &As[buf * 8192 + e * 8]);
        }
    };
    auto stageB = [&](int buf, int k0) {
#pragma unroll
        for (int i = 0; i < 2; ++i) {
            const int e   = i * 256 + tid;          // 0..511
            const int row = e >> 3;
            const int gc8 = ((e & 7) ^ (row & 7)) * 8;
            gld16(&Bw[(size_t)(n0 + row) * 1024 + k0 + gc8], &Bs[buf * 4096 + e * 8]);
        }
    };

    stageA(0, 0); stageB(0, 0);
    __syncthreads();

    const int xa = (l16 & 7) * 8;
    for (int ki = 0; ki < 16; ++ki) {
        const int cur = ki & 1;
        if (ki + 1 < 16) { stageA(cur ^ 1, (ki + 1) << 6); stageB(cur ^ 1, (ki + 1) << 6); }

#pragma unroll
        for (int ks = 0; ks < 2; ++ks) {
            const int lc = (ks * 32 + quad * 8) ^ xa;
            bf16x8 af[4], bf[2];
#pragma unroll
            for (int mi = 0; mi < 4; ++mi)
                af[mi] = *(const bf16x8*)&As[cur * 8192 + (wm * 64 + mi * 16 + l16) * 64 + lc];
#pragma unroll
            for (int ni = 0; ni < 2; ++ni)
                bf[ni] = *(const bf16x8*)&Bs[cur * 4096 + (wn * 32 + ni * 16 + l16) * 64 + lc];
#pragma unroll
            for (int mi = 0; mi < 4; ++mi)
#pragma unroll
                for (int ni = 0; ni < 2; ++ni)
                    acc[mi][ni] = __builtin_amdgcn_mfma_f32_16x16x32_bf16(af[mi], bf[ni], acc[mi][ni], 0, 0, 0);
        }
        __syncthreads();
    }

    // fp32 LDS-transpose epilogue (Tf[128][68] = 34.8 KB overlays SM)
    float* Tf = (float*)SM;
#pragma unroll
    for (int ni = 0; ni < 2; ++ni) {
        const int nloc = wn * 32 + ni * 16 + l16;
        const float bv = bias[n0 + nloc];
#pragma unroll
        for (int mi = 0; mi < 4; ++mi)
#pragma unroll
            for (int r = 0; r < 4; ++r)
                Tf[(wm * 64 + mi * 16 + quad * 4 + r) * 68 + nloc] = acc[mi][ni][r] + bv;
    }
    __syncthreads();
    {
        const int row = tid >> 1, half = tid & 1;   // rows 0..127
        const float* s = &Tf[row * 68 + half * 32];
        float* d = &Cout[(size_t)(m0 + row) * 1024 + n0 + half * 32];
#pragma unroll
        for (int j2 = 0; j2 < 8; ++j2)
            *(float4*)(d + j2 * 4) = *(const float4*)(s + j2 * 4);
    }
}

// ---------------------------------------------------------------------------
extern "C" void kernel_launch(void* const* d_in, const int* in_sizes, int n_in,
                              void* d_out, int out_size, void* d_ws, size_t ws_size,
                              hipStream_t stream)
{
    (void)in_sizes; (void)n_in; (void)out_size; (void)ws_size;

    const float* X  = (const float*)d_in[0];
    const float* Wq = (const float*)d_in[1];
    const float* bq = (const float*)d_in[2];
    const float* Wk = (const float*)d_in[3];
    const float* bk = (const float*)d_in[4];
    const float* Wv = (const float*)d_in[5];
    const float* bv = (const float*)d_in[6];
    const float* Wo = (const float*)d_in[7];
    const float* bo = (const float*)d_in[8];

    const size_t MEG = 1u << 20;
    ushort* ws    = (ushort*)d_ws;
    ushort* Xb    = ws;               // 4M
    ushort* Wcat  = ws + 4 * MEG;     // 3M  (Wq;Wk;Wv)
    ushort* Wob   = ws + 7 * MEG;     // 1M
    ushort* Qb    = ws + 8 * MEG;     // 4M  (pre-scaled by 0.125*log2e)
    ushort* Kb    = ws + 12 * MEG;    // 4M
    ushort* Vtg   = ws + 16 * MEG;    // 4M  [bh][d][s]
    ushort* Anorm = ws + 20 * MEG;    // 4M ushorts = [4096 tok][1024] bf16

    dim3 blk(256);

    convert_all<<<8192, blk, 0, stream>>>(X, Wq, Wk, Wv, Wo, Xb, Wcat, Wob);

    gemm_qkv<<<768, blk, 0, stream>>>(Xb, Wcat, bq, bk, bv,
                                      Qb, Kb, Vtg, E_DIM);

    attention16<<<1024, blk, 0, stream>>>(Qb, Kb, Vtg, Anorm);

    gemm_out<<<512, blk, 0, stream>>>(Anorm, Wob, bo, (float*)d_out);
}